// Round 21
// baseline (2355.482 us; speedup 1.0000x reference)
//
#include <hip/hip_runtime.h>

// DynamicHead R12 = R11 with ONE change: __launch_bounds__(512, 1) on the fused
// kernel. R11's counters showed the pre-committed spill fork fired: VGPR_Count
// clamped to exactly 128 (hipcc treated launch_bounds' 2nd arg as min-blocks/CU
// -> 4 waves/SIMD -> 128-VGPR cap) while the k-loop needs ~200 -> ~70 regs
// spilled to scratch -> WRITE 1.1GB / FETCH 4.1GB of spill traffic, 2287us,
// MfmaUtil 1.8%. (512,1) lifts the cap to >=256; real occupancy unchanged
// (LDS 96.7KB already limits to 1 block/CU = 2 waves/SIMD, as since R6).
// Note: a 512-thr block NEEDS 2 waves/SIMD resident, so HW bounds VGPR at 256
// regardless — (512,1) merely stops the clamp below that. ~185-reg live set fits.
// R11 mechanism under test (unchanged): B streamed global(L2)->VGPR, no B LDS,
// 1m x 8n wave tiling so each B line is read from L2 once per CU. FETCH-balloon
// risk closed by R10's data: free-running per-wave streams kept FETCH at 29MB.
// [R20 resubmission after container failure — source held fixed for attribution]

typedef __attribute__((ext_vector_type(8))) _Float16 half8;
typedef __attribute__((ext_vector_type(4))) _Float16 half4;
typedef __attribute__((ext_vector_type(4))) float floatx4;

#define XPAD 264  // halves per LDS row: 256 + 8

__device__ __forceinline__ void make_basis(float t, float* p){
  p[0] = 1.f; p[1] = t; p[2] = t*t; p[3] = p[2]*t;
  const float knots[8] = {1.f/9.f, 2.f/9.f, 3.f/9.f, 4.f/9.f,
                          5.f/9.f, 6.f/9.f, 7.f/9.f, 8.f/9.f};
  #pragma unroll
  for (int j = 0; j < 8; ++j){
    float d = t - knots[j];
    d = fmaxf(d, 0.f);
    p[4+j] = d*d*d;
  }
}

// Pack W (12,256,256) fp32 -> f16 MFMA-B-frag order via LDS transpose.
// kappa = s*8+ko; destination block position t = ko*12 + s (ko-outer stream
// order so the layer kernel's B pointer advances linearly 8192 halves/kstep).
// Within a block: halves (ntg*64 + q*16 + n16)*8 + j = f16 W[k=q*8+j][col=ntg*16+n16].
__global__ __launch_bounds__(256)
void pack_w_kernel(const float* __restrict__ W0, const float* __restrict__ W1,
                   _Float16* __restrict__ Wp0, _Float16* __restrict__ Wp1){
  __shared__ float wl[32 * 260];
  const int blk = blockIdx.x;
  const float* W = (blk < 96) ? W0 : W1;
  _Float16* Wp   = (blk < 96) ? Wp0 : Wp1;
  const int c    = (blk < 96) ? blk : blk - 96;   // kappa = s*8+ko
  const int tid  = threadIdx.x;
  const float* src = W + (size_t)c * 8192;        // 32 k-rows x 256 cols
  #pragma unroll
  for (int it = 0; it < 8; ++it){
    int idx = it * 256 + tid;          // float4 index 0..2047
    int r = idx >> 6, c4 = idx & 63;
    float4 v = *(const float4*)(src + (size_t)idx * 4);
    float* d = &wl[r * 260 + c4 * 4];
    d[0] = v.x; d[1] = v.y; d[2] = v.z; d[3] = v.w;
  }
  __syncthreads();
  const int tpos = (c & 7) * 12 + (c >> 3);       // ko*12 + s
  _Float16* dst = Wp + (size_t)tpos * 8192;
  #pragma unroll
  for (int w = 0; w < 4; ++w){
    int v = w * 256 + tid;             // 0..1023
    int n16 = v & 15, qq = (v >> 4) & 3, ntg = v >> 6;
    half8 o;
    #pragma unroll
    for (int j = 0; j < 8; ++j)
      o[j] = (_Float16)wl[(qq * 8 + j) * 260 + ntg * 16 + n16];
    *(half8*)(dst + (size_t)v * 8) = o;
  }
}

// 96-kstep GEMM pass, B direct global->VGPR. wb = Wp + wn8*1024 + lane*8
// (this lane's frag base; frag nt at +nt*512, kstep t at +t*8192).
// 3-buffer register prefetch at distance 2 (12%3==0 -> static indices).
// A-frags xc[8] reloaded once per ko (all 128 rows; 8 b128, latency amortized
// over 12 ksteps). Basis double-buffered (btlo/bthi). No barriers, no asm —
// compiler inserts waitcnts at first use (loads issued 2 ksteps early).
// Tail prefetches (t=96,97) overrun <=33KiB into the next allocated ws region.
__device__ __forceinline__ void gemm_kloop(const _Float16* Xl, const float* bldsT,
                                           const _Float16* __restrict__ wb,
                                           unsigned xbase, int l16,
                                           floatx4 acc[8][2]){
  half8 xc[8];
  half8 b[3][2];
  #pragma unroll
  for (int d = 0; d < 2; ++d)
    #pragma unroll
    for (int nt = 0; nt < 2; ++nt)
      b[d][nt] = *(const half8*)(wb + (size_t)d * 8192 + nt * 512);
  floatx4 btlo = *(const floatx4*)&bldsT[l16 * 4];        // s=0, rows mt 0..3
  floatx4 bthi = *(const floatx4*)&bldsT[64 + l16 * 4];   // s=0, rows mt 4..7

  for (int ko = 0; ko < 8; ++ko){
    #pragma unroll
    for (int s = 0; s < 12; ++s){
      const int t = ko * 12 + s;
      // prefetch B for kstep t+2 into the buffer freed at t-1
      #pragma unroll
      for (int nt = 0; nt < 2; ++nt)
        b[(s + 2) % 3][nt] =
            *(const half8*)(wb + (size_t)(t + 2) * 8192 + nt * 512);
      // prefetch basis for t+1
      const int sn = (s == 11) ? 0 : s + 1;
      floatx4 bnlo = *(const floatx4*)&bldsT[sn * 128 + l16 * 4];
      floatx4 bnhi = *(const floatx4*)&bldsT[sn * 128 + 64 + l16 * 4];
      if (s == 0){   // A-frags for this ko (reused for 12 ksteps)
        #pragma unroll
        for (int mt = 0; mt < 8; ++mt)
          xc[mt] = *(const half8*)&Xl[xbase + ko * 32 + mt * 16 * XPAD];
      }

      // kstep t: basis scale (rows mt*16+l16) then 16 MFMA, all from regs
      _Float16 bh[8];
      #pragma unroll
      for (int mt = 0; mt < 4; ++mt){
        bh[mt]     = (_Float16)btlo[mt];
        bh[4 + mt] = (_Float16)bthi[mt];
      }
      half8 az[8];
      #pragma unroll
      for (int mt = 0; mt < 8; ++mt) az[mt] = xc[mt] * bh[mt];
      #pragma unroll
      for (int mt = 0; mt < 8; ++mt)
        #pragma unroll
        for (int nt = 0; nt < 2; ++nt)
          acc[mt][nt] = __builtin_amdgcn_mfma_f32_16x16x32_f16(
              az[mt], b[s % 3][nt], acc[mt][nt], 0, 0, 0);

      btlo = bnlo; bthi = bnhi;
    }
  }
}

// acc[mt][nt] += sum_s bas_s[row] * bias[s, col]; cols = wn8*32+nt*16+l16
__device__ __forceinline__ void add_bias(const float* blds, const float* __restrict__ bias,
                                         int wn8, int q, int l16,
                                         floatx4 acc[8][2]){
  for (int s = 0; s < 12; ++s){
    float bl[2];
    #pragma unroll
    for (int nt = 0; nt < 2; ++nt)
      bl[nt] = bias[s * 256 + wn8 * 32 + nt * 16 + l16];
    #pragma unroll
    for (int mt = 0; mt < 8; ++mt){
      floatx4 bs = *(const floatx4*)&blds[s * 128 + mt * 16 + q * 4];
      #pragma unroll
      for (int nt = 0; nt < 2; ++nt)
        #pragma unroll
        for (int r = 0; r < 4; ++r)
          acc[mt][nt][r] += bs[r] * bl[nt];
    }
  }
}

// relu + scatter acc into Xl as f16 (C/D: col=lane&15 within frag, row=q*4+r)
__device__ __forceinline__ void scatter_to_xl(_Float16* Xl, floatx4 acc[8][2],
                                              int wn8, int q, int l16){
  #pragma unroll
  for (int mt = 0; mt < 8; ++mt)
    #pragma unroll
    for (int nt = 0; nt < 2; ++nt)
      #pragma unroll
      for (int r = 0; r < 4; ++r)
        Xl[(mt * 16 + q * 4 + r) * XPAD + wn8 * 32 + nt * 16 + l16] =
            (_Float16)fmaxf(acc[mt][nt][r], 0.f);
}

// Fully fused: layers 1+2 + final dot. 128 rows x 256 cols per block,
// 512 thr = 8 waves as 1(m) x 8(n): wave wn8 owns cols wn8*32..+32, all rows.
// Grid 256 -> 1 block/CU. LDS: Xl 67.5K + basis 12K + w2l 12K + red 4K = 96.3K.
// launch_bounds (512,1): LDS already limits to 1 block/CU; do NOT let the
// 2nd arg clamp VGPRs to 128 (R11 post-mortem — spill catastrophe).
__global__ __launch_bounds__(512, 1)
void fused_all_kernel(const float* __restrict__ feat, const float* __restrict__ treat,
                      const _Float16* __restrict__ Wp0, const float* __restrict__ b0,
                      const _Float16* __restrict__ Wp1, const float* __restrict__ b1,
                      const float* __restrict__ W2, const float* __restrict__ b2,
                      float* __restrict__ out){
  __shared__ _Float16 Xl[128 * XPAD];   // 67,584 B
  __shared__ float blds[12 * 128];      // 6,144 B (epilogue layout: [s][row])
  __shared__ float bldsT[12 * 128];     // 6,144 B (k-loop: [s][(r>>6)*64+(r&15)*4+((r>>4)&3)])
  __shared__ float w2l[12 * 256];       // 12,288 B (final-layer weights)
  __shared__ float redbuf[128 * 8];     // 4,096 B (cross-wave dot reduce)
  __shared__ float b2l[12];

  const int tid  = threadIdx.x;
  const int m0   = blockIdx.x * 128;
  const int lane = tid & 63;
  const int wn8  = tid >> 6;            // 0..7: cols wn8*32..+32
  const int q    = lane >> 4;
  const int l16  = lane & 15;

  // ---- stage features (128 x 256, f32 -> f16) into LDS ----
  #pragma unroll
  for (int it = 0; it < 16; ++it){
    int idx = it * 512 + tid;            // 8192 float4 chunks
    int m = idx >> 6, c = idx & 63;
    float4 v = *(const float4*)(feat + (size_t)(m0 + m) * 256 + c * 4);
    half4 h = { (_Float16)v.x, (_Float16)v.y, (_Float16)v.z, (_Float16)v.w };
    *(half4*)&Xl[m * XPAD + c * 4] = h;
  }
  // stage W2 (12x256 f32) + b2 into LDS for the fused final layer
  #pragma unroll
  for (int it = 0; it < 6; ++it)
    w2l[it * 512 + tid] = W2[it * 512 + tid];
  if (tid < 12) b2l[tid] = b2[tid];
  if (tid < 128){
    float t = treat[m0 + tid];
    float p[12]; make_basis(t, p);
    const int r   = tid;
    const int tmt = (r >> 4) & 3;
    const int tl  = r & 15;
    const int twm = r >> 6;
    #pragma unroll
    for (int s = 0; s < 12; ++s){
      blds [s * 128 + r] = p[s];
      bldsT[s * 128 + twm * 64 + tl * 4 + tmt] = p[s];
    }
  }
  __syncthreads();   // Xl + basis ready

  // A frag: row = mt*16 + l16, k = ko*32 + q*8 + j
  const unsigned xbase = (unsigned)l16 * XPAD + q * 8;
  // this lane's B stream base: quarter wn8, frag offset lane*8
  const _Float16* wb0 = Wp0 + wn8 * 1024 + lane * 8;
  const _Float16* wb1 = Wp1 + wn8 * 1024 + lane * 8;

  const floatx4 zero = {0.f, 0.f, 0.f, 0.f};
  floatx4 acc[8][2];
  #pragma unroll
  for (int mt = 0; mt < 8; ++mt)
    #pragma unroll
    for (int nt = 0; nt < 2; ++nt) acc[mt][nt] = zero;

  // ---- layer 1 ----
  gemm_kloop(Xl, bldsT, wb0, xbase, l16, acc);
  add_bias(blds, b0, wn8, q, l16, acc);
  __syncthreads();                       // all waves done reading layer-1 Xl
  scatter_to_xl(Xl, acc, wn8, q, l16);
  __syncthreads();                       // Xl rewritten with relu(x1)

  // ---- layer 2 ----
  #pragma unroll
  for (int mt = 0; mt < 8; ++mt)
    #pragma unroll
    for (int nt = 0; nt < 2; ++nt) acc[mt][nt] = zero;
  gemm_kloop(Xl, bldsT, wb1, xbase, l16, acc);
  add_bias(blds, b1, wn8, q, l16, acc);

  // ---- fused final layer: out[row] = sum_col relu(x2)*w2eff + basis.b2 ----
  #pragma unroll
  for (int mt = 0; mt < 8; ++mt)
    #pragma unroll
    for (int nt = 0; nt < 2; ++nt)
      #pragma unroll
      for (int r = 0; r < 4; ++r)
        acc[mt][nt][r] = fmaxf(acc[mt][nt][r], 0.f);
  float outp[8][4];                      // [mt][r] partial over this wave's cols
  #pragma unroll
  for (int mt = 0; mt < 8; ++mt)
    #pragma unroll
    for (int r = 0; r < 4; ++r) outp[mt][r] = 0.f;
  for (int s = 0; s < 12; ++s){
    float w2v[2];
    #pragma unroll
    for (int nt = 0; nt < 2; ++nt)
      w2v[nt] = w2l[s * 256 + wn8 * 32 + nt * 16 + l16];
    #pragma unroll
    for (int mt = 0; mt < 8; ++mt){
      floatx4 bs = *(const floatx4*)&blds[s * 128 + mt * 16 + q * 4];
      #pragma unroll
      for (int r = 0; r < 4; ++r){
        float tmp = acc[mt][0][r] * w2v[0] + acc[mt][1][r] * w2v[1];
        outp[mt][r] += bs[r] * tmp;
      }
    }
  }
  // reduce across the 16 l16-lanes within each q group (xor<16 stays in-group)
  #pragma unroll
  for (int mt = 0; mt < 8; ++mt)
    #pragma unroll
    for (int r = 0; r < 4; ++r){
      float v = outp[mt][r];
      v += __shfl_xor(v, 1, 64);
      v += __shfl_xor(v, 2, 64);
      v += __shfl_xor(v, 4, 64);
      v += __shfl_xor(v, 8, 64);
      outp[mt][r] = v;
    }
  if (l16 == 0){
    #pragma unroll
    for (int mt = 0; mt < 8; ++mt)
      #pragma unroll
      for (int r = 0; r < 4; ++r){
        int row = mt * 16 + q * 4 + r;
        redbuf[row * 8 + wn8] = outp[mt][r];
      }
  }
  __syncthreads();
  if (tid < 128){
    float v = 0.f;
    #pragma unroll
    for (int w = 0; w < 8; ++w) v += redbuf[tid * 8 + w];
    float bb = 0.f;
    #pragma unroll
    for (int s = 0; s < 12; ++s) bb += blds[s * 128 + tid] * b2l[s];
    out[m0 + tid] = v + bb;
  }
}

extern "C" void kernel_launch(void* const* d_in, const int* in_sizes, int n_in,
                              void* d_out, int out_size, void* d_ws, size_t ws_size,
                              hipStream_t stream){
  const float* treat = (const float*)d_in[0];
  const float* feat  = (const float*)d_in[1];
  const float* W0    = (const float*)d_in[2];
  const float* b0    = (const float*)d_in[3];
  const float* W1    = (const float*)d_in[4];
  const float* b1    = (const float*)d_in[5];
  const float* W2    = (const float*)d_in[6];
  const float* b2    = (const float*)d_in[7];

  char* ws = (char*)d_ws;
  _Float16* Wp0 = (_Float16*)(ws);                     // 1,572,864 B
  _Float16* Wp1 = (_Float16*)(ws + 1572864);           // 1,572,864 B (Wp0 overrun pad)
  // region past Wp1 stays allocated — absorbs the <=33KiB tail overrun
  float* out = (float*)d_out;

  pack_w_kernel<<<192, 256, 0, stream>>>(W0, W1, Wp0, Wp1);
  fused_all_kernel<<<256, 512, 0, stream>>>(feat, treat, Wp0, b0, Wp1, b1,
                                            W2, b2, out);
}

// Round 22
// 389.042 us; speedup vs baseline: 6.0546x; 6.0546x over previous
//
#include <hip/hip_runtime.h>

// DynamicHead R13 = R9's proven structure (2m x 4n waves, 88 VGPR, fused 101us)
// with ONE mechanism change: B path LDS-ring -> direct global(L2)->VGPR double
// buffer, distance-1 (full-unroll SSA renaming gives ~1 kstep of latency cover
// vs ~200cy L2 hit; dedup holds: R9/R10 FETCH 29MB). Deletes 16KB LDS write +
// 32KB LDS read per kstep and ALL k-loop barriers/vmcnt (waves free-run).
// R12/R21 lesson: hipcc pins 512-thr kernels at 128 arch-VGPRs regardless of
// launch_bounds' 2nd arg; acc[4][4] lives in AGPRs (R7-R10 reported 88).
// This kernel's non-acc live set ~98 regs -> fits the 128 envelope by design.
// Cost: wm-partner waves duplicate B quarters (32KB/kstep/CU from L2 ~45B/cyc
// at 700cy kstep, under ~56 ceiling). Everything else is R9 verbatim.

typedef __attribute__((ext_vector_type(8))) _Float16 half8;
typedef __attribute__((ext_vector_type(4))) _Float16 half4;
typedef __attribute__((ext_vector_type(4))) float floatx4;

#define XPAD 264  // halves per LDS row: 256 + 8

__device__ __forceinline__ void make_basis(float t, float* p){
  p[0] = 1.f; p[1] = t; p[2] = t*t; p[3] = p[2]*t;
  const float knots[8] = {1.f/9.f, 2.f/9.f, 3.f/9.f, 4.f/9.f,
                          5.f/9.f, 6.f/9.f, 7.f/9.f, 8.f/9.f};
  #pragma unroll
  for (int j = 0; j < 8; ++j){
    float d = t - knots[j];
    d = fmaxf(d, 0.f);
    p[4+j] = d*d*d;
  }
}

// Pack W (12,256,256) fp32 -> f16 MFMA-B-frag order via LDS transpose.
// kappa = s*8+ko; destination block position t = ko*12 + s (ko-outer stream
// order so the layer kernel's B pointer advances linearly 8192 halves/kstep).
__global__ __launch_bounds__(256)
void pack_w_kernel(const float* __restrict__ W0, const float* __restrict__ W1,
                   _Float16* __restrict__ Wp0, _Float16* __restrict__ Wp1){
  __shared__ float wl[32 * 260];
  const int blk = blockIdx.x;
  const float* W = (blk < 96) ? W0 : W1;
  _Float16* Wp   = (blk < 96) ? Wp0 : Wp1;
  const int c    = (blk < 96) ? blk : blk - 96;   // kappa = s*8+ko
  const int tid  = threadIdx.x;
  const float* src = W + (size_t)c * 8192;        // 32 k-rows x 256 cols
  #pragma unroll
  for (int it = 0; it < 8; ++it){
    int idx = it * 256 + tid;          // float4 index 0..2047
    int r = idx >> 6, c4 = idx & 63;
    float4 v = *(const float4*)(src + (size_t)idx * 4);
    float* d = &wl[r * 260 + c4 * 4];
    d[0] = v.x; d[1] = v.y; d[2] = v.z; d[3] = v.w;
  }
  __syncthreads();
  const int tpos = (c & 7) * 12 + (c >> 3);       // ko*12 + s
  _Float16* dst = Wp + (size_t)tpos * 8192;
  #pragma unroll
  for (int w = 0; w < 4; ++w){
    int v = w * 256 + tid;             // 0..1023
    int n16 = v & 15, qq = (v >> 4) & 3, ntg = v >> 6;
    half8 o;
    #pragma unroll
    for (int j = 0; j < 8; ++j)
      o[j] = (_Float16)wl[(qq * 8 + j) * 260 + ntg * 16 + n16];
    *(half8*)(dst + (size_t)v * 8) = o;
  }
}

// 96-kstep GEMM pass. B direct global->VGPR, double-buffered at distance 1:
// iter t issues loads for t+1 (full s-unroll renames bc<-bn, so the waitcnt
// lands at t+1's first MFMA use — ~1 kstep of cover > L2 ~200cy). A-frags
// xc[4] reloaded once per ko. No barriers, no asm. wb = this lane's frag
// base (Wp + wn*2048 + lane*8); frag nt at +nt*512, kstep t at +t*8192.
// Tail prefetch (t=96) overruns <=16KiB into the next allocated ws region.
__device__ __forceinline__ void gemm_kloop(const _Float16* Xl, const float* bldsT,
                                           const _Float16* __restrict__ wb,
                                           unsigned xbase, int wm, int l16,
                                           floatx4 acc[4][4]){
  half8 xc[4], xn[4], bc[4], bn[4];
  #pragma unroll
  for (int nt = 0; nt < 4; ++nt)
    bc[nt] = *(const half8*)(wb + nt * 512);            // kstep 0
  #pragma unroll
  for (int mt = 0; mt < 4; ++mt)
    xc[mt] = *(const half8*)&Xl[xbase + mt * 16 * XPAD];
  floatx4 btc = *(const floatx4*)&bldsT[wm * 64 + l16 * 4]; // s = 0

  for (int ko = 0; ko < 8; ++ko){
    #pragma unroll
    for (int s = 0; s < 12; ++s){
      const int t = ko * 12 + s;
      // prefetch B for kstep t+1 (retires under this kstep's MFMA block)
      #pragma unroll
      for (int nt = 0; nt < 4; ++nt)
        bn[nt] = *(const half8*)(wb + (size_t)(t + 1) * 8192 + nt * 512);
      // prefetch basis for t+1
      const int sn = (s == 11) ? 0 : s + 1;
      floatx4 btn = *(const floatx4*)&bldsT[sn * 128 + wm * 64 + l16 * 4];
      if (s == 0){   // next ko's A-frags (needed 12 ksteps later)
        const int kon = (ko + 1) & 7;   // wraps at ko=7; result discarded
        #pragma unroll
        for (int mt = 0; mt < 4; ++mt)
          xn[mt] = *(const half8*)&Xl[xbase + kon * 32 + mt * 16 * XPAD];
      }

      // kstep t: basis scale then 16 MFMA, all from regs
      _Float16 bh[4];
      #pragma unroll
      for (int mt = 0; mt < 4; ++mt) bh[mt] = (_Float16)btc[mt];
      half8 az[4];
      #pragma unroll
      for (int mt = 0; mt < 4; ++mt) az[mt] = xc[mt] * bh[mt];
      #pragma unroll
      for (int mt = 0; mt < 4; ++mt)
        #pragma unroll
        for (int nt = 0; nt < 4; ++nt)
          acc[mt][nt] = __builtin_amdgcn_mfma_f32_16x16x32_f16(
              az[mt], bc[nt], acc[mt][nt], 0, 0, 0);

      // rotate double buffers (renamed away by the full unroll)
      #pragma unroll
      for (int nt = 0; nt < 4; ++nt) bc[nt] = bn[nt];
      btc = btn;
      if (s == 11){
        #pragma unroll
        for (int mt = 0; mt < 4; ++mt) xc[mt] = xn[mt];
      }
    }
  }
}

// acc[mt][nt] += sum_s bas_s[row] * bias[s, col]
__device__ __forceinline__ void add_bias(const float* blds, const float* __restrict__ bias,
                                         int wm, int wn, int q, int l16,
                                         floatx4 acc[4][4]){
  for (int s = 0; s < 12; ++s){
    float bl[4];
    #pragma unroll
    for (int nt = 0; nt < 4; ++nt)
      bl[nt] = bias[s * 256 + wn * 64 + nt * 16 + l16];
    floatx4 bs[4];
    #pragma unroll
    for (int mt = 0; mt < 4; ++mt)
      bs[mt] = *(const floatx4*)&blds[s * 128 + wm * 64 + mt * 16 + q * 4];
    #pragma unroll
    for (int mt = 0; mt < 4; ++mt)
      #pragma unroll
      for (int nt = 0; nt < 4; ++nt)
        #pragma unroll
        for (int r = 0; r < 4; ++r)
          acc[mt][nt][r] += bs[mt][r] * bl[nt];
  }
}

// relu + scatter acc into Xl as f16 (C/D layout: col=lane&15, row=(lane>>4)*4+r)
__device__ __forceinline__ void scatter_to_xl(_Float16* Xl, floatx4 acc[4][4],
                                              int wm, int wn, int q, int l16){
  #pragma unroll
  for (int mt = 0; mt < 4; ++mt)
    #pragma unroll
    for (int nt = 0; nt < 4; ++nt)
      #pragma unroll
      for (int r = 0; r < 4; ++r)
        Xl[(wm * 64 + mt * 16 + q * 4 + r) * XPAD + wn * 64 + nt * 16 + l16] =
            (_Float16)fmaxf(acc[mt][nt][r], 0.f);
}

// Fully fused: layers 1+2 as MFMA GEMMs + final (out dim 1) in the epilogue.
// 128 rows x 256 cols per block, 512 thr = 8 waves (2m x 4n). Grid 256, 1/CU.
// LDS: Xl 67.5K + basis 12K + w2l 12K + red 2K = 93.9K (no B LDS).
__global__ __launch_bounds__(512)
void fused_all_kernel(const float* __restrict__ feat, const float* __restrict__ treat,
                      const _Float16* __restrict__ Wp0, const float* __restrict__ b0,
                      const _Float16* __restrict__ Wp1, const float* __restrict__ b1,
                      const float* __restrict__ W2, const float* __restrict__ b2,
                      float* __restrict__ out){
  __shared__ _Float16 Xl[128 * XPAD];   // 67,584 B
  __shared__ float blds[12 * 128];      // 6,144 B (epilogue layout)
  __shared__ float bldsT[12 * 128];     // 6,144 B (k-loop layout)
  __shared__ float w2l[12 * 256];       // 12,288 B (final-layer weights)
  __shared__ float redbuf[128 * 4];     // 2,048 B (cross-wave dot reduce)
  __shared__ float b2l[12];

  const int tid  = threadIdx.x;
  const int m0   = blockIdx.x * 128;
  const int lane = tid & 63;
  const int wid  = tid >> 6;
  const int wm   = wid >> 2;            // 0..1: rows wm*64..+64
  const int wn   = wid & 3;             // 0..3: cols wn*64..+64
  const int q    = lane >> 4;
  const int l16  = lane & 15;

  // ---- stage features (128 x 256, f32 -> f16) into LDS ----
  #pragma unroll
  for (int it = 0; it < 16; ++it){
    int idx = it * 512 + tid;            // 8192 float4 chunks
    int m = idx >> 6, c = idx & 63;
    float4 v = *(const float4*)(feat + (size_t)(m0 + m) * 256 + c * 4);
    half4 h = { (_Float16)v.x, (_Float16)v.y, (_Float16)v.z, (_Float16)v.w };
    *(half4*)&Xl[m * XPAD + c * 4] = h;
  }
  // stage W2 (12x256 f32) + b2 into LDS for the fused final layer
  #pragma unroll
  for (int it = 0; it < 6; ++it)
    w2l[it * 512 + tid] = W2[it * 512 + tid];
  if (tid < 12) b2l[tid] = b2[tid];
  if (tid < 128){
    float t = treat[m0 + tid];
    float p[12]; make_basis(t, p);
    const int r   = tid;
    const int tmt = (r >> 4) & 3;        // row's mt index within its wm half
    const int tl  = r & 15;              // row's l16
    const int twm = r >> 6;
    #pragma unroll
    for (int s = 0; s < 12; ++s){
      blds [s * 128 + r] = p[s];
      bldsT[s * 128 + twm * 64 + tl * 4 + tmt] = p[s];
    }
  }
  __syncthreads();   // Xl + basis ready

  // A frag: row = wm*64 + mt*16 + l16, k = ko*32 + q*8 + j (halves in Xl)
  const unsigned xbase = (unsigned)(wm * 64 + l16) * XPAD + q * 8;
  // this lane's B stream base: quarter wn, frag offset lane*8
  const _Float16* wb0 = Wp0 + wn * 2048 + lane * 8;
  const _Float16* wb1 = Wp1 + wn * 2048 + lane * 8;

  const floatx4 zero = {0.f, 0.f, 0.f, 0.f};
  floatx4 acc[4][4];
  #pragma unroll
  for (int mt = 0; mt < 4; ++mt)
    #pragma unroll
    for (int nt = 0; nt < 4; ++nt) acc[mt][nt] = zero;

  // ---- layer 1 ----
  gemm_kloop(Xl, bldsT, wb0, xbase, wm, l16, acc);
  add_bias(blds, b0, wm, wn, q, l16, acc);
  __syncthreads();                       // all waves done reading layer-1 Xl
  scatter_to_xl(Xl, acc, wm, wn, q, l16);
  __syncthreads();                       // Xl rewritten with relu(x1)

  // ---- layer 2 ----
  #pragma unroll
  for (int mt = 0; mt < 4; ++mt)
    #pragma unroll
    for (int nt = 0; nt < 4; ++nt) acc[mt][nt] = zero;
  gemm_kloop(Xl, bldsT, wb1, xbase, wm, l16, acc);
  add_bias(blds, b1, wm, wn, q, l16, acc);

  // ---- fused final layer: out[row] = sum_col relu(x2)*w2eff + basis.b2 ----
  #pragma unroll
  for (int mt = 0; mt < 4; ++mt)
    #pragma unroll
    for (int nt = 0; nt < 4; ++nt)
      #pragma unroll
      for (int r = 0; r < 4; ++r)
        acc[mt][nt][r] = fmaxf(acc[mt][nt][r], 0.f);
  // per-thread partial dot: this thread holds rows (mt,r), cols (nt)
  float outp[4][4];                      // [mt][r]
  #pragma unroll
  for (int mt = 0; mt < 4; ++mt)
    #pragma unroll
    for (int r = 0; r < 4; ++r) outp[mt][r] = 0.f;
  for (int s = 0; s < 12; ++s){
    float w2v[4];
    #pragma unroll
    for (int nt = 0; nt < 4; ++nt)
      w2v[nt] = w2l[s * 256 + wn * 64 + nt * 16 + l16];
    floatx4 bs[4];
    #pragma unroll
    for (int mt = 0; mt < 4; ++mt)
      bs[mt] = *(const floatx4*)&blds[s * 128 + wm * 64 + mt * 16 + q * 4];
    #pragma unroll
    for (int mt = 0; mt < 4; ++mt)
      #pragma unroll
      for (int r = 0; r < 4; ++r){
        float tmp = acc[mt][0][r] * w2v[0] + acc[mt][1][r] * w2v[1]
                  + acc[mt][2][r] * w2v[2] + acc[mt][3][r] * w2v[3];
        outp[mt][r] += bs[mt][r] * tmp;
      }
  }
  // reduce across the 16 l16-lanes of each q group
  #pragma unroll
  for (int mt = 0; mt < 4; ++mt)
    #pragma unroll
    for (int r = 0; r < 4; ++r){
      float v = outp[mt][r];
      v += __shfl_xor(v, 1, 64);
      v += __shfl_xor(v, 2, 64);
      v += __shfl_xor(v, 4, 64);
      v += __shfl_xor(v, 8, 64);
      outp[mt][r] = v;
    }
  if (l16 == 0){
    #pragma unroll
    for (int mt = 0; mt < 4; ++mt)
      #pragma unroll
      for (int r = 0; r < 4; ++r){
        int row = wm * 64 + mt * 16 + q * 4 + r;
        redbuf[row * 4 + wn] = outp[mt][r];
      }
  }
  __syncthreads();
  if (tid < 128){
    float v = redbuf[tid * 4 + 0] + redbuf[tid * 4 + 1]
            + redbuf[tid * 4 + 2] + redbuf[tid * 4 + 3];
    float bb = 0.f;
    #pragma unroll
    for (int s = 0; s < 12; ++s) bb += blds[s * 128 + tid] * b2l[s];
    out[m0 + tid] = v + bb;
  }
}

extern "C" void kernel_launch(void* const* d_in, const int* in_sizes, int n_in,
                              void* d_out, int out_size, void* d_ws, size_t ws_size,
                              hipStream_t stream){
  const float* treat = (const float*)d_in[0];
  const float* feat  = (const float*)d_in[1];
  const float* W0    = (const float*)d_in[2];
  const float* b0    = (const float*)d_in[3];
  const float* W1    = (const float*)d_in[4];
  const float* b1    = (const float*)d_in[5];
  const float* W2    = (const float*)d_in[6];
  const float* b2    = (const float*)d_in[7];

  char* ws = (char*)d_ws;
  _Float16* Wp0 = (_Float16*)(ws);                     // 1,572,864 B
  _Float16* Wp1 = (_Float16*)(ws + 1572864);           // 1,572,864 B (Wp0 overrun pad)
  // region past Wp1 stays allocated — absorbs the <=16KiB tail overrun
  float* out = (float*)d_out;

  pack_w_kernel<<<192, 256, 0, stream>>>(W0, W1, Wp0, Wp1);
  fused_all_kernel<<<256, 512, 0, stream>>>(feat, treat, Wp0, b0, Wp1, b1,
                                            W2, b2, out);
}